// Round 1
// baseline (315.748 us; speedup 1.0000x reference)
//
#include <hip/hip_runtime.h>

// ---------- types & helpers ----------
typedef unsigned short u16;
typedef float f32x4 __attribute__((ext_vector_type(4)));
typedef short s16x8 __attribute__((ext_vector_type(8)));
typedef unsigned short u16x4 __attribute__((ext_vector_type(4)));

__device__ __forceinline__ u16 f2bf(float f) {
  union { float f; unsigned u; } v; v.f = f;
  unsigned r = v.u + 0x7FFFu + ((v.u >> 16) & 1u);   // RNE
  return (u16)(r >> 16);
}

__device__ __forceinline__ void gload_lds16(const void* g, void* l) {
  __builtin_amdgcn_global_load_lds(
      (const __attribute__((address_space(1))) void*)g,
      (__attribute__((address_space(3))) void*)l, 16, 0, 0);
}

// ---------- fp32 -> bf16 cast ----------
__global__ __launch_bounds__(256) void cast_f32_bf16(
    const float* __restrict__ src, u16* __restrict__ dst, int n4) {
  int i = blockIdx.x * 256 + threadIdx.x;
  if (i >= n4) return;
  f32x4 v = ((const f32x4*)src)[i];
  u16x4 o = { f2bf(v[0]), f2bf(v[1]), f2bf(v[2]), f2bf(v[3]) };
  ((u16x4*)dst)[i] = o;
}

// ---------- bt-GEMM: C[M,N] = A[M,K] * B[N,K]^T  (bf16 in, fp32 acc) ----------
// 128x128 tile, BK=32, 256 threads (4 waves in 2x2), m97 structure.
// FINAL=0: bf16 C, no bias.  FINAL=1: fp32 C + bias[col].
template <int FINAL>
__global__ __launch_bounds__(256) void gemm_bt(
    const u16* __restrict__ A, const u16* __restrict__ B,
    void* __restrict__ Cout, const float* __restrict__ bias,
    int K, int lda, int ldb, int ldc) {
  __shared__ u16 As[128 * 32];
  __shared__ u16 Bs[128 * 32];
  const int tid = threadIdx.x;
  const int wid = tid >> 6, lane = tid & 63;
  const int lo = lane & 15, hi = lane >> 4;
  const int wr = wid >> 1, wc = wid & 1;
  const long brow = (long)blockIdx.y * 128;
  const long bcol = (long)blockIdx.x * 128;

  f32x4 acc[4][4] = {};

  const char* Ab = (const char*)(A + (size_t)brow * lda);
  const char* Bb = (const char*)(B + (size_t)bcol * ldb);
  const int ldab = lda * 2, ldbb = ldb * 2;

  for (int k0 = 0; k0 < K; k0 += 32) {
#pragma unroll
    for (int i = 0; i < 2; ++i) {
      int ob = wid * 2048 + i * 1024;    // wave-uniform LDS base
      int o = ob + lane * 16;
      int row = o >> 6, cb = o & 63;
      gload_lds16(Ab + (size_t)row * ldab + k0 * 2 + cb, (char*)As + ob);
      gload_lds16(Bb + (size_t)row * ldbb + k0 * 2 + cb, (char*)Bs + ob);
    }
    __syncthreads();   // drains vmcnt(0) then barrier
    s16x8 af[4], bfr[4];
#pragma unroll
    for (int m = 0; m < 4; ++m)
      af[m] = *(const s16x8*)&As[(wr * 64 + m * 16 + lo) * 32 + hi * 8];
#pragma unroll
    for (int n = 0; n < 4; ++n)
      bfr[n] = *(const s16x8*)&Bs[(wc * 64 + n * 16 + lo) * 32 + hi * 8];
#pragma unroll
    for (int m = 0; m < 4; ++m)
#pragma unroll
      for (int n = 0; n < 4; ++n)
        acc[m][n] = __builtin_amdgcn_mfma_f32_16x16x32_bf16(af[m], bfr[n], acc[m][n], 0, 0, 0);
    __syncthreads();
  }
#pragma unroll
  for (int m = 0; m < 4; ++m) {
#pragma unroll
    for (int n = 0; n < 4; ++n) {
#pragma unroll
      for (int r = 0; r < 4; ++r) {
        size_t row = brow + wr * 64 + m * 16 + hi * 4 + r;
        size_t col = bcol + wc * 64 + n * 16 + lo;
        float v = acc[m][n][r];
        if (FINAL) ((float*)Cout)[row * ldc + col] = v + bias[col];
        else       ((u16*)Cout)[row * ldc + col] = f2bf(v);
      }
    }
  }
}

// ---------- Ke/Vf: per (kc, b*h, type) block computes 64k x 64d ----------
// KeT[bh][k][d] = sum_n We[h][k][n]*K[bh][n][d] + bE   (type 0)
// Vf [bh][d][k] = sum_n Wf[h][k][n]*V[bh][n][d] + bF   (type 1)
__global__ __launch_bounds__(256) void kevf_kernel(
    const float* __restrict__ We, const float* __restrict__ bE,
    const float* __restrict__ Wf, const float* __restrict__ bF,
    const u16* __restrict__ QKV, u16* __restrict__ KeT, u16* __restrict__ Vf) {
  __shared__ u16 Wa[64 * 32];   // [kk][n] bf16, xor-swizzled 16B slots
  __shared__ u16 Vt[64 * 32];   // [dd][n] bf16, n xor-swizzled by dd
  const int type = blockIdx.z;
  const int bh = blockIdx.y, b = bh >> 4, h = bh & 15;
  const int kk0 = blockIdx.x * 64;
  const float* W = (type ? Wf : We) + ((size_t)(h * 256 + kk0)) * 4096;
  const float* bias = (type ? bF : bE) + h * 256 + kk0;
  const int col0 = (type ? 2048 : 1024) + h * 64;
  const int tid = threadIdx.x, wid = tid >> 6, lane = tid & 63;
  const int lo = lane & 15, hi = lane >> 4;

  f32x4 acc[4] = {};

  for (int n0 = 0; n0 < 4096; n0 += 32) {
    { // stage W (fp32 -> bf16)
      int r = tid >> 2, c8 = (tid & 3) * 8;
      const f32x4* wp = (const f32x4*)(W + (size_t)r * 4096 + n0 + c8);
      f32x4 v0 = wp[0], v1 = wp[1];
      s16x8 wv;
      wv[0] = (short)f2bf(v0[0]); wv[1] = (short)f2bf(v0[1]);
      wv[2] = (short)f2bf(v0[2]); wv[3] = (short)f2bf(v0[3]);
      wv[4] = (short)f2bf(v1[0]); wv[5] = (short)f2bf(v1[1]);
      wv[6] = (short)f2bf(v1[2]); wv[7] = (short)f2bf(v1[3]);
      *(s16x8*)((char*)Wa + r * 64 + ((c8 * 2) ^ ((r & 3) << 4))) = wv;
    }
    { // stage V/K transposed
      int n = tid >> 3, dd0 = (tid & 7) * 8;
      s16x8 v = *(const s16x8*)(QKV + (size_t)(b * 4096 + n0 + n) * 3072 + col0 + dd0);
#pragma unroll
      for (int q = 0; q < 8; ++q) {
        int dd = dd0 + q;
        Vt[dd * 32 + (n ^ (((dd >> 3) & 3) << 3))] = (u16)v[q];
      }
    }
    __syncthreads();
    int rr = wid * 16 + lo;
    s16x8 a = *(const s16x8*)((const char*)Wa + rr * 64 + ((hi * 16) ^ ((rr & 3) << 4)));
#pragma unroll
    for (int dt = 0; dt < 4; ++dt) {
      int dd = dt * 16 + lo;
      s16x8 bv = *(const s16x8*)&Vt[dd * 32 + ((hi * 8) ^ (((dd >> 3) & 3) << 3))];
      acc[dt] = __builtin_amdgcn_mfma_f32_16x16x32_bf16(a, bv, acc[dt], 0, 0, 0);
    }
    __syncthreads();
  }
#pragma unroll
  for (int dt = 0; dt < 4; ++dt) {
#pragma unroll
    for (int r = 0; r < 4; ++r) {
      int kkl = wid * 16 + hi * 4 + r;
      int dd = dt * 16 + lo;
      float v = acc[dt][r] + bias[kkl];
      if (type == 0) KeT[((size_t)bh * 256 + kk0 + kkl) * 64 + dd] = f2bf(v);
      else           Vf[((size_t)bh * 64 + dd) * 256 + kk0 + kkl] = f2bf(v);
    }
  }
}

// ---------- fused attention: scores -> softmax -> PV -> gelu ----------
// grid (64 ntiles, 32 bh); 256 threads = 4 waves x 16 q-rows each.
__global__ __launch_bounds__(256) void attn_fused(
    const u16* __restrict__ QKV, const u16* __restrict__ KeT,
    const u16* __restrict__ Vf, u16* __restrict__ attn) {
  __shared__ char smem[65536];
  char* sKe = smem;           // [256][128B] swizzled (aliased by P later)
  char* sVf = smem + 32768;   // [64][512B] swizzled
  const int tid = threadIdx.x, wid = tid >> 6, lane = tid & 63;
  const int lo = lane & 15, hi = lane >> 4;
  const int bh = blockIdx.y, b = bh >> 4, h = bh & 15;
  const int n0 = blockIdx.x * 64;

  const char* keg = (const char*)(KeT + (size_t)bh * 256 * 64);
  const char* vfg = (const char*)(Vf + (size_t)bh * 64 * 256);
#pragma unroll
  for (int i = 0; i < 8; ++i) {
    int ob = wid * 8192 + i * 1024;
    int o = ob + lane * 16;
    int kr = o >> 7, kc = o & 127;
    gload_lds16(keg + kr * 128 + (kc ^ ((kr & 7) << 4)), sKe + ob);
    int vr = o >> 9, vc = o & 511;
    gload_lds16(vfg + vr * 512 + (vc ^ ((vr & 7) << 4)), sVf + ob);
  }
  const u16* qp = QKV + (size_t)(b * 4096 + n0 + wid * 16 + lo) * 3072 + h * 64;
  s16x8 qf0 = *(const s16x8*)(qp + hi * 8);
  s16x8 qf1 = *(const s16x8*)(qp + 32 + hi * 8);
  __syncthreads();

  f32x4 sc[16];
#pragma unroll
  for (int nt = 0; nt < 16; ++nt) {
    int kk = nt * 16 + lo;
    int sw = (kk & 7) << 4;
    s16x8 b0 = *(const s16x8*)(sKe + kk * 128 + ((hi * 16) ^ sw));
    s16x8 b1 = *(const s16x8*)(sKe + kk * 128 + ((64 + hi * 16) ^ sw));
    f32x4 c = {0.f, 0.f, 0.f, 0.f};
    c = __builtin_amdgcn_mfma_f32_16x16x32_bf16(qf0, b0, c, 0, 0, 0);
    c = __builtin_amdgcn_mfma_f32_16x16x32_bf16(qf1, b1, c, 0, 0, 0);
    sc[nt] = c;
  }
  // softmax over 256 (rows live on 16-lane groups: row = hi*4+r, col = nt*16+lo)
  float mx[4], inv[4];
#pragma unroll
  for (int r = 0; r < 4; ++r) {
    float m = sc[0][r];
#pragma unroll
    for (int nt = 1; nt < 16; ++nt) m = fmaxf(m, sc[nt][r]);
    m = fmaxf(m, __shfl_xor(m, 1));
    m = fmaxf(m, __shfl_xor(m, 2));
    m = fmaxf(m, __shfl_xor(m, 4));
    m = fmaxf(m, __shfl_xor(m, 8));
    mx[r] = m;
  }
  const float SCL = 0.125f * 1.4426950408889634f;   // (1/sqrt(64)) * log2(e)
  float sm[4] = {0.f, 0.f, 0.f, 0.f};
#pragma unroll
  for (int nt = 0; nt < 16; ++nt)
#pragma unroll
    for (int r = 0; r < 4; ++r) {
      float p = exp2f((sc[nt][r] - mx[r]) * SCL);
      sc[nt][r] = p;
      sm[r] += p;
    }
#pragma unroll
  for (int r = 0; r < 4; ++r) {
    float s = sm[r];
    s += __shfl_xor(s, 1);
    s += __shfl_xor(s, 2);
    s += __shfl_xor(s, 4);
    s += __shfl_xor(s, 8);
    inv[r] = 1.0f / s;
  }
  __syncthreads();            // all waves done reading sKe
  char* pb = smem + wid * 8192;  // P aliases sKe region: [16 rows][512B] per wave
#pragma unroll
  for (int nt = 0; nt < 16; ++nt)
#pragma unroll
    for (int r = 0; r < 4; ++r) {
      int row = hi * 4 + r;
      int kk = nt * 16 + lo;
      *(u16*)(pb + row * 512 + ((kk * 2) ^ ((row & 7) << 4))) = f2bf(sc[nt][r] * inv[r]);
    }
  __syncthreads();
  s16x8 pa[8];
#pragma unroll
  for (int ks = 0; ks < 8; ++ks)
    pa[ks] = *(const s16x8*)(pb + lo * 512 + ((ks * 64 + hi * 16) ^ ((lo & 7) << 4)));
#pragma unroll
  for (int dt = 0; dt < 4; ++dt) {
    int dd = dt * 16 + lo;
    int sw = (dd & 7) << 4;
    f32x4 o = {0.f, 0.f, 0.f, 0.f};
#pragma unroll
    for (int ks = 0; ks < 8; ++ks) {
      s16x8 vb = *(const s16x8*)(sVf + dd * 512 + ((ks * 64 + hi * 16) ^ sw));
      o = __builtin_amdgcn_mfma_f32_16x16x32_bf16(pa[ks], vb, o, 0, 0, 0);
    }
#pragma unroll
    for (int r = 0; r < 4; ++r) {
      int row = n0 + wid * 16 + hi * 4 + r;
      float x = o[r];
      float g = 0.5f * x * (1.0f + erff(x * 0.7071067811865476f));
      attn[(size_t)(b * 4096 + row) * 1024 + h * 64 + dd] = f2bf(g);
    }
  }
}

// ---------- launcher ----------
extern "C" void kernel_launch(void* const* d_in, const int* in_sizes, int n_in,
                              void* d_out, int out_size, void* d_ws, size_t ws_size,
                              hipStream_t stream) {
  const float* x  = (const float*)d_in[0];
  const float* Wq = (const float*)d_in[1];
  const float* Wk = (const float*)d_in[2];
  const float* Wv = (const float*)d_in[3];
  const float* We = (const float*)d_in[4];
  const float* bE = (const float*)d_in[5];
  const float* Wf = (const float*)d_in[6];
  const float* bF = (const float*)d_in[7];
  const float* Wo = (const float*)d_in[8];
  const float* bo = (const float*)d_in[9];
  float* out = (float*)d_out;

  char* ws = (char*)d_ws;
  u16* xb   = (u16*)(ws);                 // 16,777,216 B  [8192][1024] bf16
  u16* Wqkv = (u16*)(ws + 16777216);      //  6,291,456 B  [3072][1024] bf16
  u16* Wob  = (u16*)(ws + 23068672);      //  2,097,152 B  [1024][1024] bf16
  u16* QKV  = (u16*)(ws + 25165824);      // 50,331,648 B  [8192][3072] bf16
  u16* KeT  = (u16*)(ws + 75497472);      //  1,048,576 B  [32][256][64] bf16
  u16* Vf   = (u16*)(ws + 76546048);      //  1,048,576 B  [32][64][256] bf16
  u16* attn = (u16*)(ws + 77594624);      // 16,777,216 B  [8192][1024] bf16

  cast_f32_bf16<<<8192, 256, 0, stream>>>(x, xb, 2097152);
  cast_f32_bf16<<<1024, 256, 0, stream>>>(Wq, Wqkv, 262144);
  cast_f32_bf16<<<1024, 256, 0, stream>>>(Wk, Wqkv + 1048576, 262144);
  cast_f32_bf16<<<1024, 256, 0, stream>>>(Wv, Wqkv + 2097152, 262144);
  cast_f32_bf16<<<1024, 256, 0, stream>>>(Wo, Wob, 262144);

  // QKV projection: [8192,3072] = x[8192,1024] @ Wqkv[3072,1024]^T
  gemm_bt<0><<<dim3(24, 64), 256, 0, stream>>>(xb, Wqkv, QKV, nullptr,
                                               1024, 1024, 1024, 3072);
  // Ke/Vf low-rank projections
  kevf_kernel<<<dim3(4, 32, 2), 256, 0, stream>>>(We, bE, Wf, bF, QKV, KeT, Vf);
  // fused scores/softmax/PV/gelu
  attn_fused<<<dim3(64, 32), 256, 0, stream>>>(QKV, KeT, Vf, attn);
  // output projection + bias
  gemm_bt<1><<<dim3(8, 64), 256, 0, stream>>>(attn, Wob, out, bo,
                                              1024, 1024, 1024, 1024);
}